// Round 2
// baseline (500.981 us; speedup 1.0000x reference)
//
#include <hip/hip_runtime.h>
#include <math.h>

#define F_IN 128
constexpr int SB = 256;

__global__ void zero_int(int* p, int n) {
    int i = blockIdx.x * 256 + threadIdx.x;
    if (i < n) p[i] = 0;
}

// deg[i] = in-degree of node i (original edges + self loop)
__global__ void count_deg(const int* __restrict__ dst, int* __restrict__ deg, int E, int N) {
    int e = blockIdx.x * 256 + threadIdx.x;
    if (e < E) atomicAdd(&deg[dst[e]], 1);
    else if (e < E + N) atomicAdd(&deg[e - E], 1);
}

// 3-kernel exclusive scan over n elements (n <= SB*SB)
__global__ void scan1(const int* __restrict__ in, int* __restrict__ out,
                      int* __restrict__ bsums, int n) {
    __shared__ int sm[SB];
    int i = blockIdx.x * SB + threadIdx.x;
    int v = (i < n) ? in[i] : 0;
    sm[threadIdx.x] = v;
    __syncthreads();
    for (int d = 1; d < SB; d <<= 1) {
        int t = (threadIdx.x >= d) ? sm[threadIdx.x - d] : 0;
        __syncthreads();
        sm[threadIdx.x] += t;
        __syncthreads();
    }
    if (i < n) out[i] = sm[threadIdx.x] - v;   // exclusive
    if (threadIdx.x == SB - 1) bsums[blockIdx.x] = sm[SB - 1];
}

__global__ void scan2(int* __restrict__ bsums, int nb) {
    __shared__ int sm[SB];
    int v = (threadIdx.x < nb) ? bsums[threadIdx.x] : 0;
    sm[threadIdx.x] = v;
    __syncthreads();
    for (int d = 1; d < SB; d <<= 1) {
        int t = (threadIdx.x >= d) ? sm[threadIdx.x - d] : 0;
        __syncthreads();
        sm[threadIdx.x] += t;
        __syncthreads();
    }
    if (threadIdx.x < nb) bsums[threadIdx.x] = sm[threadIdx.x] - v;  // exclusive
}

__global__ void scan3(int* __restrict__ off, int* __restrict__ cursor,
                      const int* __restrict__ bsums, int n, int ncur) {
    int i = blockIdx.x * SB + threadIdx.x;
    if (i < n) {
        int v = off[i] + bsums[blockIdx.x];
        off[i] = v;
        if (i < ncur) cursor[i] = v;
    }
}

__global__ void scatter_csr(const int* __restrict__ src, const int* __restrict__ dst,
                            int* __restrict__ cursor, int* __restrict__ csr_src,
                            int E, int N) {
    int e = blockIdx.x * 256 + threadIdx.x;
    if (e < E) {
        int p = atomicAdd(&cursor[dst[e]], 1);
        csr_src[p] = src[e];
    } else if (e < E + N) {
        int i = e - E;
        int p = atomicAdd(&cursor[i], 1);
        csr_src[p] = i;
    }
}

// C[M,NC] = A[M,K] * B[K,NC]. One thread per column j; RPB rows per thread.
// A loads are wave-uniform -> scalar loads; B loads coalesced.
template <int K, int NC, int RPB>
__global__ void gemm_rt(const float* __restrict__ A, const float* __restrict__ B,
                        float* __restrict__ C, int M) {
    int j = threadIdx.x;
    int row0 = (blockIdx.x * blockDim.y + threadIdx.y) * RPB;
    const float* Ar[RPB];
#pragma unroll
    for (int r = 0; r < RPB; ++r) {
        int row = row0 + r;
        if (row > M - 1) row = M - 1;  // clamp (tail blocks); store is guarded
        Ar[r] = A + (size_t)row * K;
    }
    float acc[RPB];
#pragma unroll
    for (int r = 0; r < RPB; ++r) acc[r] = 0.f;
    for (int k = 0; k < K; ++k) {
        float b = B[k * NC + j];
#pragma unroll
        for (int r = 0; r < RPB; ++r) acc[r] += Ar[r][k] * b;
    }
#pragma unroll
    for (int r = 0; r < RPB; ++r) {
        int row = row0 + r;
        if (row < M) C[(size_t)row * NC + j] = acc[r];
    }
}

// Per-(node,head) attention logit contributions
template <int HEADS, int OC>
__global__ void calc_al(const float* __restrict__ h, const float* __restrict__ a_src,
                        const float* __restrict__ a_dst, float* __restrict__ als,
                        float* __restrict__ ald, int n) {
    int t = blockIdx.x * blockDim.x + threadIdx.x;
    int node = t / HEADS, hd = t % HEADS;
    if (node >= n) return;
    const float* hp = h + (size_t)node * HEADS * OC + hd * OC;
    float s = 0.f, d = 0.f;
#pragma unroll
    for (int c = 0; c < OC; ++c) {
        float v = hp[c];
        s += v * a_src[hd * OC + c];
        d += v * a_dst[hd * OC + c];
    }
    als[node * HEADS + hd] = s;
    ald[node * HEADS + hd] = d;
}

// One wave per destination node. Single pass: accumulate numerator S and
// denominator D of the segment softmax simultaneously (max-shift not needed,
// logits are O(1)). Fused bias + optional ELU.
template <int HEADS, int OC, bool APPLY_ELU>
__global__ void gat_agg(const float* __restrict__ h, const float* __restrict__ als,
                        const float* __restrict__ ald, const float* __restrict__ bias,
                        const int* __restrict__ off, const int* __restrict__ csr_src,
                        float* __restrict__ out, int n) {
    constexpr int C = HEADS * OC;       // 128 or 64
    constexpr int CPL = (C + 63) / 64;  // channels per lane: 2 or 1
    int wid = (blockIdx.x * blockDim.x + threadIdx.x) >> 6;
    int lane = threadIdx.x & 63;
    if (wid >= n) return;
    int i = wid;
    int e0 = off[i], e1 = off[i + 1];
    int ch[CPL], hd[CPL];
    float aldv[CPL], S[CPL], D[CPL];
#pragma unroll
    for (int p = 0; p < CPL; ++p) {
        ch[p] = lane + 64 * p;
        hd[p] = ch[p] / OC;
        aldv[p] = ald[i * HEADS + hd[p]];
        S[p] = 0.f;
        D[p] = 0.f;
    }
    for (int e = e0; e < e1; ++e) {
        int s = csr_src[e];
#pragma unroll
        for (int p = 0; p < CPL; ++p) {
            float lg = als[s * HEADS + hd[p]] + aldv[p];
            lg = lg > 0.f ? lg : 0.2f * lg;
            float ex = __expf(lg);
            D[p] += ex;
            S[p] += ex * h[(size_t)s * C + ch[p]];
        }
    }
#pragma unroll
    for (int p = 0; p < CPL; ++p) {
        float v = S[p] / D[p] + bias[ch[p]];
        if (APPLY_ELU) v = v > 0.f ? v : (__expf(v) - 1.f);
        out[(size_t)i * C + ch[p]] = v;
    }
}

// Layer-3 feature (single head, single channel): h3 = a2 @ W3, plus logit terms
__global__ void layer3_h(const float* __restrict__ a2, const float* __restrict__ W3,
                         const float* __restrict__ as3, const float* __restrict__ ad3,
                         float* __restrict__ h3, float* __restrict__ als,
                         float* __restrict__ ald, int n) {
    int i = blockIdx.x * blockDim.x + threadIdx.x;
    if (i >= n) return;
    const float* ap = a2 + (size_t)i * 64;
    float s = 0.f;
#pragma unroll
    for (int k = 0; k < 64; ++k) s += ap[k] * W3[k];
    h3[i] = s;
    als[i] = s * as3[0];
    ald[i] = s * ad3[0];
}

// Layer-3 aggregation: scalar channel, one thread per node
__global__ void gat_agg1(const float* __restrict__ h, const float* __restrict__ als,
                         const float* __restrict__ ald, const float* __restrict__ bias,
                         const int* __restrict__ off, const int* __restrict__ csr_src,
                         float* __restrict__ out, int n) {
    int i = blockIdx.x * blockDim.x + threadIdx.x;
    if (i >= n) return;
    float ad = ald[i];
    float S = 0.f, D = 0.f;
    int e1 = off[i + 1];
    for (int e = off[i]; e < e1; ++e) {
        int s = csr_src[e];
        float lg = als[s] + ad;
        lg = lg > 0.f ? lg : 0.2f * lg;
        float ex = __expf(lg);
        D += ex;
        S += ex * h[s];
    }
    out[i] = S / D + bias[0];
}

extern "C" void kernel_launch(void* const* d_in, const int* in_sizes, int n_in,
                              void* d_out, int out_size, void* d_ws, size_t ws_size,
                              hipStream_t stream) {
    const float* x   = (const float*)d_in[0];
    const int*   ei  = (const int*)d_in[1];
    const float* W1  = (const float*)d_in[2];
    const float* as1 = (const float*)d_in[3];
    const float* ad1 = (const float*)d_in[4];
    const float* b1  = (const float*)d_in[5];
    const float* W2  = (const float*)d_in[6];
    const float* as2 = (const float*)d_in[7];
    const float* ad2 = (const float*)d_in[8];
    const float* b2  = (const float*)d_in[9];
    const float* W3  = (const float*)d_in[10];
    const float* as3 = (const float*)d_in[11];
    const float* ad3 = (const float*)d_in[12];
    const float* b3  = (const float*)d_in[13];
    float* out = (float*)d_out;

    const int N = in_sizes[0] / F_IN;  // 50000
    const int E = in_sizes[1] / 2;     // 800000
    const int ET = E + N;

    char* w = (char*)d_ws;
    size_t o = 0;
    auto alloc = [&](size_t bytes) -> void* {
        void* p = w + o;
        o += (bytes + 255) & ~(size_t)255;
        return p;
    };
    float* h1  = (float*)alloc((size_t)N * 128 * 4);
    float* a1  = (float*)alloc((size_t)N * 128 * 4);
    float* h2  = (float*)alloc((size_t)N * 64 * 4);
    float* a2  = (float*)alloc((size_t)N * 64 * 4);
    float* h3  = (float*)alloc((size_t)N * 4);
    float* als = (float*)alloc((size_t)N * 4 * 4);
    float* ald = (float*)alloc((size_t)N * 4 * 4);
    int* deg    = (int*)alloc((size_t)(N + 1) * 4);
    int* off    = (int*)alloc((size_t)(N + 1) * 4);
    int* cursor = (int*)alloc((size_t)N * 4);
    int* bsums  = (int*)alloc(1024);
    int* csr    = (int*)alloc((size_t)ET * 4);

    const int* esrc = ei;
    const int* edst = ei + E;

    // ---- CSR build (dst-sorted incoming-edge lists) ----
    zero_int<<<(N + 1 + 255) / 256, 256, 0, stream>>>(deg, N + 1);
    count_deg<<<(ET + 255) / 256, 256, 0, stream>>>(edst, deg, E, N);
    int n1 = N + 1;
    int nb = (n1 + SB - 1) / SB;
    scan1<<<nb, SB, 0, stream>>>(deg, off, bsums, n1);
    scan2<<<1, SB, 0, stream>>>(bsums, nb);
    scan3<<<nb, SB, 0, stream>>>(off, cursor, bsums, n1, N);
    scatter_csr<<<(ET + 255) / 256, 256, 0, stream>>>(esrc, edst, cursor, csr, E, N);

    // ---- Layer 1: 128 -> 4 heads x 32, concat, ELU ----
    gemm_rt<128, 128, 8><<<dim3((N + 15) / 16), dim3(128, 2), 0, stream>>>(x, W1, h1, N);
    calc_al<4, 32><<<(N * 4 + 255) / 256, 256, 0, stream>>>(h1, as1, ad1, als, ald, N);
    gat_agg<4, 32, true><<<(N * 64 + 255) / 256, 256, 0, stream>>>(
        h1, als, ald, b1, off, csr, a1, N);

    // ---- Layer 2: 128 -> 2 heads x 32, concat, ELU ----
    gemm_rt<128, 64, 8><<<dim3((N + 31) / 32), dim3(64, 4), 0, stream>>>(a1, W2, h2, N);
    calc_al<2, 32><<<(N * 2 + 255) / 256, 256, 0, stream>>>(h2, as2, ad2, als, ald, N);
    gat_agg<2, 32, true><<<(N * 64 + 255) / 256, 256, 0, stream>>>(
        h2, als, ald, b2, off, csr, a2, N);

    // ---- Layer 3: 64 -> 1, mean over 1 head (identity), + b3 ----
    layer3_h<<<(N + 255) / 256, 256, 0, stream>>>(a2, W3, as3, ad3, h3, als, ald, N);
    gat_agg1<<<(N + 255) / 256, 256, 0, stream>>>(h3, als, ald, b3, off, csr, out, N);
}

// Round 3
// 298.183 us; speedup vs baseline: 1.6801x; 1.6801x over previous
//
#include <hip/hip_runtime.h>
#include <math.h>

#define F_IN 128
constexpr int SB = 256;

__global__ void zero_int(int* p, int n) {
    int i = blockIdx.x * 256 + threadIdx.x;
    if (i < n) p[i] = 0;
}

__global__ void count_deg(const int* __restrict__ dst, int* __restrict__ deg, int E, int N) {
    int e = blockIdx.x * 256 + threadIdx.x;
    if (e < E) atomicAdd(&deg[dst[e]], 1);
    else if (e < E + N) atomicAdd(&deg[e - E], 1);
}

// 3-kernel exclusive scan over n elements (n <= SB*SB)
__global__ void scan1(const int* __restrict__ in, int* __restrict__ out,
                      int* __restrict__ bsums, int n) {
    __shared__ int sm[SB];
    int i = blockIdx.x * SB + threadIdx.x;
    int v = (i < n) ? in[i] : 0;
    sm[threadIdx.x] = v;
    __syncthreads();
    for (int d = 1; d < SB; d <<= 1) {
        int t = (threadIdx.x >= d) ? sm[threadIdx.x - d] : 0;
        __syncthreads();
        sm[threadIdx.x] += t;
        __syncthreads();
    }
    if (i < n) out[i] = sm[threadIdx.x] - v;
    if (threadIdx.x == SB - 1) bsums[blockIdx.x] = sm[SB - 1];
}

__global__ void scan2(int* __restrict__ bsums, int nb) {
    __shared__ int sm[SB];
    int v = (threadIdx.x < nb) ? bsums[threadIdx.x] : 0;
    sm[threadIdx.x] = v;
    __syncthreads();
    for (int d = 1; d < SB; d <<= 1) {
        int t = (threadIdx.x >= d) ? sm[threadIdx.x - d] : 0;
        __syncthreads();
        sm[threadIdx.x] += t;
        __syncthreads();
    }
    if (threadIdx.x < nb) bsums[threadIdx.x] = sm[threadIdx.x] - v;
}

__global__ void scan3(int* __restrict__ off, int* __restrict__ cursor,
                      const int* __restrict__ bsums, int n, int ncur) {
    int i = blockIdx.x * SB + threadIdx.x;
    if (i < n) {
        int v = off[i] + bsums[blockIdx.x];
        off[i] = v;
        if (i < ncur) cursor[i] = v;
    }
}

__global__ void scatter_csr(const int* __restrict__ src, const int* __restrict__ dst,
                            int* __restrict__ cursor, int* __restrict__ csr_src,
                            int E, int N) {
    int e = blockIdx.x * 256 + threadIdx.x;
    if (e < E) {
        int p = atomicAdd(&cursor[dst[e]], 1);
        csr_src[p] = src[e];
    } else if (e < E + N) {
        int i = e - E;
        int p = atomicAdd(&cursor[i], 1);
        csr_src[p] = i;
    }
}

// LDS-tiled GEMM, C[M,BN] = A[M,128] * B[128,BN], fused per-(row,head)
// attention-logit epilogue: als/ald[row][h] = sum_c C[row][h*32+c]*a{src,dst}[h*32+c].
// Block (16,32)=512 thr; BM=128 (ty*4 rows), cols = tx*TN.
template <int BN, int TN, int HEADS>
__global__ __launch_bounds__(512) void gemm_fused(
    const float* __restrict__ A, const float* __restrict__ B,
    const float* __restrict__ asrc, const float* __restrict__ adst,
    float* __restrict__ C, float* __restrict__ als, float* __restrict__ ald,
    int M) {
    constexpr int BM = 128, BK = 16, TM = 4, K = 128, OC = 32;
    constexpr int GROUP = OC / TN;  // x-lanes per head
    __shared__ float As[BK][BM + 4];  // transposed, padded: 16B-aligned rows
    __shared__ float Bs[BK][BN];
    const int tx = threadIdx.x, ty = threadIdx.y;
    const int tid = ty * 16 + tx;
    const int row0 = blockIdx.x * BM;
    const int i0 = ty * TM;
    const int j0 = tx * TN;

    float acc[TM][TN];
#pragma unroll
    for (int m = 0; m < TM; ++m)
#pragma unroll
        for (int n = 0; n < TN; ++n) acc[m][n] = 0.f;

    // A staging map: 1 float4/thread/chunk
    const int ar = tid >> 2;        // tile row 0..127
    const int ak = (tid & 3) * 4;   // k offset
    int arow = row0 + ar;
    if (arow >= M) arow = M - 1;
    const float* Aptr = A + (size_t)arow * K + ak;
    // B staging map
    const int bk = (BN == 128) ? (tid >> 5) : (tid >> 4);
    const int bc = (BN == 128) ? ((tid & 31) * 4) : ((tid & 15) * 4);
    const bool bact = (BN == 128) || (tid < 256);

    for (int kc = 0; kc < K; kc += BK) {
        float4 av = *(const float4*)(Aptr + kc);
        float4 bv;
        if (bact) bv = *(const float4*)(B + (size_t)(kc + bk) * BN + bc);
        __syncthreads();
        As[ak + 0][ar] = av.x;
        As[ak + 1][ar] = av.y;
        As[ak + 2][ar] = av.z;
        As[ak + 3][ar] = av.w;
        if (bact) *(float4*)&Bs[bk][bc] = bv;
        __syncthreads();
#pragma unroll
        for (int kk = 0; kk < BK; ++kk) {
            float4 a4 = *(const float4*)&As[kk][i0];
            float arr[TM] = {a4.x, a4.y, a4.z, a4.w};
            float br[TN];
            float4 b0 = *(const float4*)&Bs[kk][j0];
            br[0] = b0.x; br[1] = b0.y; br[2] = b0.z; br[3] = b0.w;
            if constexpr (TN == 8) {
                float4 b1 = *(const float4*)&Bs[kk][j0 + 4];
                br[4] = b1.x; br[5] = b1.y; br[6] = b1.z; br[7] = b1.w;
            }
#pragma unroll
            for (int m = 0; m < TM; ++m)
#pragma unroll
                for (int n = 0; n < TN; ++n) acc[m][n] += arr[m] * br[n];
        }
    }

    const int h0 = j0 / OC;
#pragma unroll
    for (int m = 0; m < TM; ++m) {
        int row = row0 + i0 + m;
        bool ok = row < M;
        if (ok) {
            float4 c0;
            c0.x = acc[m][0]; c0.y = acc[m][1]; c0.z = acc[m][2]; c0.w = acc[m][3];
            *(float4*)&C[(size_t)row * BN + j0] = c0;
            if constexpr (TN == 8) {
                float4 c1;
                c1.x = acc[m][4]; c1.y = acc[m][5]; c1.z = acc[m][6]; c1.w = acc[m][7];
                *(float4*)&C[(size_t)row * BN + j0 + 4] = c1;
            }
        }
        float ps = 0.f, pd = 0.f;
#pragma unroll
        for (int n = 0; n < TN; ++n) {
            ps += acc[m][n] * asrc[j0 + n];
            pd += acc[m][n] * adst[j0 + n];
        }
#pragma unroll
        for (int msk = 1; msk < GROUP; msk <<= 1) {
            ps += __shfl_xor(ps, msk, 64);
            pd += __shfl_xor(pd, msk, 64);
        }
        if (ok && (tx & (GROUP - 1)) == 0) {
            als[row * HEADS + h0] = ps;
            ald[row * HEADS + h0] = pd;
        }
    }
}

// Layer-1 aggregation: one wave per dst node, 2 channels/lane via float2.
// Single-pass softmax (numerator+denominator together), fused bias+ELU.
__global__ void gat_agg_l1(const float* __restrict__ h, const float* __restrict__ als,
                           const float* __restrict__ ald, const float* __restrict__ bias,
                           const int* __restrict__ off, const int* __restrict__ csr_src,
                           float* __restrict__ out, int n) {
    int wid = (blockIdx.x * blockDim.x + threadIdx.x) >> 6;
    int lane = threadIdx.x & 63;
    if (wid >= n) return;
    const int hd = lane >> 4;  // head of channels (2*lane, 2*lane+1), OC=32
    float ad = ald[wid * 4 + hd];
    const float2* h2 = (const float2*)h;
    float Sx = 0.f, Sy = 0.f, D = 0.f;
    int e0 = off[wid], e1 = off[wid + 1];
    int s = csr_src[e0];  // degree >= 1 (self-loop)
    for (int e = e0; e < e1; ++e) {
        int sn = (e + 1 < e1) ? csr_src[e + 1] : s;
        float lg = als[s * 4 + hd] + ad;
        lg = lg > 0.f ? lg : 0.2f * lg;
        float ex = __expf(lg);
        float2 hv = h2[(size_t)s * 64 + lane];
        D += ex;
        Sx += ex * hv.x;
        Sy += ex * hv.y;
        s = sn;
    }
    float2 bv = ((const float2*)bias)[lane];
    float vx = Sx / D + bv.x, vy = Sy / D + bv.y;
    vx = vx > 0.f ? vx : (__expf(vx) - 1.f);
    vy = vy > 0.f ? vy : (__expf(vy) - 1.f);
    float2 o; o.x = vx; o.y = vy;
    ((float2*)out)[(size_t)wid * 64 + lane] = o;
}

// Layer-2 aggregation (C=64, HEADS=2) with fused layer-3 feature head:
// a2 never materialized; h3 = sum_c elu(agg+b2)[c] * W3[c] via wave reduce.
__global__ void gat_agg_l2(const float* __restrict__ h, const float* __restrict__ als,
                           const float* __restrict__ ald, const float* __restrict__ bias,
                           const int* __restrict__ off, const int* __restrict__ csr_src,
                           const float* __restrict__ W3, const float* __restrict__ as3,
                           const float* __restrict__ ad3, float* __restrict__ h3,
                           float* __restrict__ als3, float* __restrict__ ald3, int n) {
    int wid = (blockIdx.x * blockDim.x + threadIdx.x) >> 6;
    int lane = threadIdx.x & 63;
    if (wid >= n) return;
    const int hd = lane >> 5;  // channel = lane, OC=32
    float ad = ald[wid * 2 + hd];
    float S = 0.f, D = 0.f;
    int e0 = off[wid], e1 = off[wid + 1];
    int s = csr_src[e0];
    for (int e = e0; e < e1; ++e) {
        int sn = (e + 1 < e1) ? csr_src[e + 1] : s;
        float lg = als[s * 2 + hd] + ad;
        lg = lg > 0.f ? lg : 0.2f * lg;
        float ex = __expf(lg);
        float hv = h[(size_t)s * 64 + lane];
        D += ex;
        S += ex * hv;
        s = sn;
    }
    float v = S / D + bias[lane];
    v = v > 0.f ? v : (__expf(v) - 1.f);     // ELU -> this is a2[wid][lane]
    float r = v * W3[lane];
#pragma unroll
    for (int msk = 1; msk < 64; msk <<= 1) r += __shfl_xor(r, msk, 64);
    if (lane == 0) {
        h3[wid] = r;
        als3[wid] = r * as3[0];
        ald3[wid] = r * ad3[0];
    }
}

// Layer-3 aggregation: scalar channel, one thread per node
__global__ void gat_agg1(const float* __restrict__ h, const float* __restrict__ als,
                         const float* __restrict__ ald, const float* __restrict__ bias,
                         const int* __restrict__ off, const int* __restrict__ csr_src,
                         float* __restrict__ out, int n) {
    int i = blockIdx.x * blockDim.x + threadIdx.x;
    if (i >= n) return;
    float ad = ald[i];
    float S = 0.f, D = 0.f;
    int e0 = off[i], e1 = off[i + 1];
    int s = csr_src[e0];
    for (int e = e0; e < e1; ++e) {
        int sn = (e + 1 < e1) ? csr_src[e + 1] : s;
        float lg = als[s] + ad;
        lg = lg > 0.f ? lg : 0.2f * lg;
        float ex = __expf(lg);
        D += ex;
        S += ex * h[s];
        s = sn;
    }
    out[i] = S / D + bias[0];
}

extern "C" void kernel_launch(void* const* d_in, const int* in_sizes, int n_in,
                              void* d_out, int out_size, void* d_ws, size_t ws_size,
                              hipStream_t stream) {
    const float* x   = (const float*)d_in[0];
    const int*   ei  = (const int*)d_in[1];
    const float* W1  = (const float*)d_in[2];
    const float* as1 = (const float*)d_in[3];
    const float* ad1 = (const float*)d_in[4];
    const float* b1  = (const float*)d_in[5];
    const float* W2  = (const float*)d_in[6];
    const float* as2 = (const float*)d_in[7];
    const float* ad2 = (const float*)d_in[8];
    const float* b2  = (const float*)d_in[9];
    const float* W3  = (const float*)d_in[10];
    const float* as3 = (const float*)d_in[11];
    const float* ad3 = (const float*)d_in[12];
    const float* b3  = (const float*)d_in[13];
    float* out = (float*)d_out;

    const int N = in_sizes[0] / F_IN;  // 50000
    const int E = in_sizes[1] / 2;     // 800000
    const int ET = E + N;

    char* w = (char*)d_ws;
    size_t o = 0;
    auto alloc = [&](size_t bytes) -> void* {
        void* p = w + o;
        o += (bytes + 255) & ~(size_t)255;
        return p;
    };
    float* h1   = (float*)alloc((size_t)N * 128 * 4);
    float* a1   = (float*)alloc((size_t)N * 128 * 4);
    float* h2   = (float*)alloc((size_t)N * 64 * 4);
    float* h3   = (float*)alloc((size_t)N * 4);
    float* als  = (float*)alloc((size_t)N * 4 * 4);
    float* ald  = (float*)alloc((size_t)N * 4 * 4);
    float* als3 = (float*)alloc((size_t)N * 4);
    float* ald3 = (float*)alloc((size_t)N * 4);
    int* deg    = (int*)alloc((size_t)(N + 1) * 4);
    int* off    = (int*)alloc((size_t)(N + 1) * 4);
    int* cursor = (int*)alloc((size_t)N * 4);
    int* bsums  = (int*)alloc(1024);
    int* csr    = (int*)alloc((size_t)ET * 4);

    const int* esrc = ei;
    const int* edst = ei + E;

    // ---- CSR build (dst-sorted incoming-edge lists) ----
    zero_int<<<(N + 1 + 255) / 256, 256, 0, stream>>>(deg, N + 1);
    count_deg<<<(ET + 255) / 256, 256, 0, stream>>>(edst, deg, E, N);
    int n1 = N + 1;
    int nb = (n1 + SB - 1) / SB;
    scan1<<<nb, SB, 0, stream>>>(deg, off, bsums, n1);
    scan2<<<1, SB, 0, stream>>>(bsums, nb);
    scan3<<<nb, SB, 0, stream>>>(off, cursor, bsums, n1, N);
    scatter_csr<<<(ET + 255) / 256, 256, 0, stream>>>(esrc, edst, cursor, csr, E, N);

    const int gblk = (N + 127) / 128;

    // ---- Layer 1: 128 -> 4 heads x 32, concat, ELU ----
    gemm_fused<128, 8, 4><<<gblk, dim3(16, 32), 0, stream>>>(
        x, W1, as1, ad1, h1, als, ald, N);
    gat_agg_l1<<<(N * 64 + 255) / 256, 256, 0, stream>>>(
        h1, als, ald, b1, off, csr, a1, N);

    // ---- Layer 2: 128 -> 2 heads x 32, concat, ELU (+ fused layer-3 head) ----
    gemm_fused<64, 4, 2><<<gblk, dim3(16, 32), 0, stream>>>(
        a1, W2, as2, ad2, h2, als, ald, N);
    gat_agg_l2<<<(N * 64 + 255) / 256, 256, 0, stream>>>(
        h2, als, ald, b2, off, csr, W3, as3, ad3, h3, als3, ald3, N);

    // ---- Layer 3: aggregation of scalar feature ----
    gat_agg1<<<(N + 255) / 256, 256, 0, stream>>>(h3, als3, ald3, b3, off, csr, out, N);
}